// Round 8
// baseline (1933.090 us; speedup 1.0000x reference)
//
#include <hip/hip_runtime.h>
#include <hip/hip_bf16.h>
#include <math.h>

#define B_  16
#define S_  512
#define D_  768
#define H_  12
#define DN_ 64
#define F_  3072
#define L_  6
#define T_  (B_*S_)          // 8192 tokens
#define QKVN 2304            // 3*D
#define TDC ((size_t)T_*D_)  // 6,291,456

typedef unsigned short ushort_t;
typedef short short8 __attribute__((ext_vector_type(8)));
typedef float floatx4 __attribute__((ext_vector_type(4)));

#define LDS_AS(p) ((__attribute__((address_space(3))) void*)(p))
#define GLB_AS(p) ((const __attribute__((address_space(1))) void*)(p))

static __device__ __forceinline__ float b2f(ushort_t u) {
  union { unsigned int i; float f; } x; x.i = ((unsigned int)u) << 16; return x.f;
}
static __device__ __forceinline__ ushort_t f2b(float f) {
  union { float f; unsigned int i; } x; x.f = f;
  unsigned int r = x.i + 0x7fffu + ((x.i >> 16) & 1u);   // RNE
  return (ushort_t)(r >> 16);
}

// ---------------------------------------------------------------------------
__global__ __launch_bounds__(64) void probe_x(const int* __restrict__ x,
                                              int* __restrict__ xstride) {
  if (threadIdx.x == 0) {
    int allzero = 1;
    for (int i = 0; i < 64; ++i) allzero &= (x[2 * i + 1] == 0) ? 1 : 0;
    *xstride = allzero ? 2 : 1;
  }
}

// ---------------------------------------------------------------------------
// One-time positional-encoding table pe[S][D] (f32).
// ---------------------------------------------------------------------------
__global__ __launch_bounds__(256) void pe_kernel(float* __restrict__ pe) {
  const int s = blockIdx.x;
  const float pos = (float)s;
  for (int d = threadIdx.x; d < D_; d += 256) {
    float v;
    if ((d & 1) == 0) {
      float freq = powf(10000.0f, -(float)d * (1.0f / 768.0f));
      v = sinf(pos * freq);
    } else {
      float freq = powf(10000.0f, -(float)(d + 1) * (1.0f / 768.0f));
      v = cosf(pos * freq);
    }
    pe[(size_t)s * D_ + d] = v;
  }
}

// ---------------------------------------------------------------------------
__global__ __launch_bounds__(256) void embed_pe(const int* __restrict__ x,
                                                const int* __restrict__ xstride,
                                                const float* __restrict__ emb,
                                                const float* __restrict__ pe,
                                                float* __restrict__ h32,
                                                ushort_t* __restrict__ h16) {
  const int t = blockIdx.x;
  const int s = t & (S_ - 1);
  const int tok = x[t * (*xstride)];
  const float* ep = emb + (size_t)tok * D_;
  const float* pp = pe + (size_t)s * D_;
  for (int d = threadIdx.x; d < D_; d += 256) {
    float v = ep[d] + pp[d];
    h32[(size_t)t * D_ + d] = v;
    h16[(size_t)t * D_ + d] = f2b(v);
  }
}

// ---------------------------------------------------------------------------
// Bit-pack padding mask: mask[B][S][S] (int 0/1) -> bits[B*S][8] uint64.
// ---------------------------------------------------------------------------
__global__ __launch_bounds__(256) void mask_bits(const int* __restrict__ mask,
                                                 unsigned long long* __restrict__ bits) {
  const int gw = (blockIdx.x * 256 + threadIdx.x) >> 6;   // global wave id
  const int lane = threadIdx.x & 63;
  const int m = mask[(size_t)gw * 64 + lane];
  unsigned long long bal = __ballot(m != 0);
  if (lane == 0) bits[gw] = bal;
}

// ---------------------------------------------------------------------------
// pack bq/bk/bv [L][768] each -> bqkv [L][2304]
// ---------------------------------------------------------------------------
__global__ __launch_bounds__(256) void pack_bias(const float* __restrict__ bq,
                                                 const float* __restrict__ bk,
                                                 const float* __restrict__ bv,
                                                 float* __restrict__ bqkv) {
  const int i = blockIdx.x * 256 + threadIdx.x;   // l*768+c, i < 4608
  if (i < L_ * D_) {
    const int l = i / D_, c = i - l * D_;
    bqkv[(size_t)l * QKVN + c]          = bq[i];
    bqkv[(size_t)l * QKVN + 768 + c]    = bk[i];
    bqkv[(size_t)l * QKVN + 1536 + c]   = bv[i];
  }
}

// ---------------------------------------------------------------------------
// Batched transpose-cast fp32 [z][R][C] -> bf16 out rows.
// ---------------------------------------------------------------------------
__global__ __launch_bounds__(256) void transpose_cast(const float* __restrict__ in,
                                                      ushort_t* __restrict__ out,
                                                      int R, int C, int ZH,
                                                      size_t strideL, size_t strideH) {
  __shared__ float tb[32][33];
  const int c0 = blockIdx.x * 32, r0 = blockIdx.y * 32;
  const int z = blockIdx.z;
  const float* ib = in + (size_t)z * R * C;
  ushort_t* ob = out + (size_t)(z / ZH) * strideL + (size_t)(z % ZH) * strideH;
  const int i = threadIdx.x >> 5;
  const int j = threadIdx.x & 31;
  #pragma unroll
  for (int t = 0; t < 4; ++t)
    tb[i + 8 * t][j] = ib[(size_t)(r0 + i + 8 * t) * C + c0 + j];
  __syncthreads();
  #pragma unroll
  for (int t = 0; t < 4; ++t)
    ob[(size_t)(c0 + i + 8 * t) * R + r0 + j] = f2b(tb[j][i + 8 * t]);
}

// ---------------------------------------------------------------------------
// qkv [B*S][2304] (v at +1536) -> vT [B*H][64 e][512 s]
// ---------------------------------------------------------------------------
__global__ __launch_bounds__(256) void transpose_v(const ushort_t* __restrict__ qkv,
                                                   ushort_t* __restrict__ vT) {
  __shared__ ushort_t tb[32][33];
  const int s0 = blockIdx.x * 32, e0 = blockIdx.y * 32;
  const int bh = blockIdx.z;
  const int b = bh / 12, hh = bh - b * 12;
  const int i = threadIdx.x >> 5, j = threadIdx.x & 31;
  #pragma unroll
  for (int t = 0; t < 4; ++t)
    tb[i + 8 * t][j] = qkv[((size_t)(b * S_ + s0 + i + 8 * t)) * QKVN + 1536 + hh * 64 + e0 + j];
  __syncthreads();
  #pragma unroll
  for (int t = 0; t < 4; ++t)
    vT[((size_t)(bh * 64 + e0 + i + 8 * t)) * S_ + s0 + j] = tb[j][i + 8 * t];
}

// ---------------------------------------------------------------------------
// MFMA GEMM: C[M,N](bf16) = A[M,K](bf16) @ Bt[N,K]^T + bias(f32), RELU opt.
// 128x128 tile, BK=64, 4 waves, both-sides XOR swizzle (bank-conflict-free).
// T3-minimum schedule: double-buffered LDS; next tile's global_load_lds
// issued BEFORE computing current tile; ONE __syncthreads per K-step (its
// implicit vmcnt(0) drains the prefetch that had the whole compute to land).
// ---------------------------------------------------------------------------
template<int RELU>
__global__ __launch_bounds__(256) void gemm_mfma(const ushort_t* __restrict__ A,
                                                 const ushort_t* __restrict__ Bt,
                                                 const float* __restrict__ bias,
                                                 ushort_t* __restrict__ C,
                                                 int N, int K) {
  __shared__ ushort_t Alds[2][128 * 64];
  __shared__ ushort_t Blds[2][128 * 64];
  const int tid = threadIdx.x;
  const int lane = tid & 63, wave = tid >> 6;
  const int l16 = lane & 15, quad = lane >> 4;
  const int m0 = (wave >> 1) * 64, n0 = (wave & 1) * 64;
  const int nb = gridDim.x;
  const int flat = blockIdx.y * nb + blockIdx.x;
  const int grp = flat / (8 * nb);
  const int rem = flat - grp * 8 * nb;
  const int bm = (grp * 8 + (rem & 7)) * 128;
  const int bn = (rem >> 3) * 128;
  const int r0 = tid >> 3;
  const int ch = tid & 7;
  const int koff = (ch ^ (r0 & 7)) * 8;      // pre-swizzled source column

  const ushort_t* ga = A  + (size_t)(bm + r0) * K + koff;
  const ushort_t* gb = Bt + (size_t)(bn + r0) * K + koff;
  const int ldst = tid * 8;                  // per-thread LDS slot (16B)
  const int swz = l16 & 7;
  const int NT = K >> 6;

  floatx4 acc[4][4] = {};
  // prologue: stage tile 0 into buffer 0, drain
  #pragma unroll
  for (int j = 0; j < 4; ++j) {
    __builtin_amdgcn_global_load_lds(GLB_AS(ga + (size_t)(j * 32) * K), LDS_AS(&Alds[0][ldst + j * 2048]), 16, 0, 0);
    __builtin_amdgcn_global_load_lds(GLB_AS(gb + (size_t)(j * 32) * K), LDS_AS(&Blds[0][ldst + j * 2048]), 16, 0, 0);
  }
  __syncthreads();

  int cur = 0;
  for (int t = 0; t < NT; ++t) {
    if (t + 1 < NT) {   // issue next tile's loads; latency hides under MFMA
      const int k0 = (t + 1) << 6;
      #pragma unroll
      for (int j = 0; j < 4; ++j) {
        __builtin_amdgcn_global_load_lds(GLB_AS(ga + k0 + (size_t)(j * 32) * K), LDS_AS(&Alds[cur ^ 1][ldst + j * 2048]), 16, 0, 0);
        __builtin_amdgcn_global_load_lds(GLB_AS(gb + k0 + (size_t)(j * 32) * K), LDS_AS(&Blds[cur ^ 1][ldst + j * 2048]), 16, 0, 0);
      }
    }
    #pragma unroll
    for (int kk = 0; kk < 2; ++kk) {
      short8 af[4], bf[4];
      #pragma unroll
      for (int fi = 0; fi < 4; ++fi) {
        const int row = m0 + fi * 16 + l16;
        af[fi] = *(const short8*)&Alds[cur][row * 64 + ((((kk << 2) + quad) ^ swz) * 8)];
      }
      #pragma unroll
      for (int fj = 0; fj < 4; ++fj) {
        const int row = n0 + fj * 16 + l16;
        bf[fj] = *(const short8*)&Blds[cur][row * 64 + ((((kk << 2) + quad) ^ swz) * 8)];
      }
      #pragma unroll
      for (int fi = 0; fi < 4; ++fi)
        #pragma unroll
        for (int fj = 0; fj < 4; ++fj)
          acc[fi][fj] = __builtin_amdgcn_mfma_f32_16x16x32_bf16(af[fi], bf[fj], acc[fi][fj], 0, 0, 0);
    }
    __syncthreads();    // vmcnt(0): next tile landed; all waves done with cur
    cur ^= 1;
  }
  #pragma unroll
  for (int fi = 0; fi < 4; ++fi) {
    #pragma unroll
    for (int fj = 0; fj < 4; ++fj) {
      const int row = bm + m0 + fi * 16 + quad * 4;
      const int col = bn + n0 + fj * 16 + l16;
      const float bv = bias[col];
      #pragma unroll
      for (int r = 0; r < 4; ++r) {
        float v = acc[fi][fj][r] + bv;
        if (RELU) v = fmaxf(v, 0.0f);
        C[(size_t)(row + r) * N + col] = f2b(v);
      }
    }
  }
}

// ---------------------------------------------------------------------------
// Split-K (x2) variant for grid-starved N=768 GEMMs (Wo, FF2).
// Same T3-minimum double-buffered schedule.
// ---------------------------------------------------------------------------
__global__ __launch_bounds__(256) void gemm_mfma_sk(const ushort_t* __restrict__ A,
                                                    const ushort_t* __restrict__ Bt,
                                                    const float* __restrict__ bias,
                                                    ushort_t* __restrict__ P,
                                                    int N, int K) {
  __shared__ ushort_t Alds[2][128 * 64];
  __shared__ ushort_t Blds[2][128 * 64];
  const int tid = threadIdx.x;
  const int lane = tid & 63, wave = tid >> 6;
  const int l16 = lane & 15, quad = lane >> 4;
  const int m0 = (wave >> 1) * 64, n0 = (wave & 1) * 64;
  const int nb = gridDim.x;
  const int flat = blockIdx.y * nb + blockIdx.x;
  const int grp = flat / (8 * nb);
  const int rem = flat - grp * 8 * nb;
  const int bm = (grp * 8 + (rem & 7)) * 128;
  const int bn = (rem >> 3) * 128;
  const int r0 = tid >> 3;
  const int ch = tid & 7;
  const int koff = (ch ^ (r0 & 7)) * 8;
  const int z = blockIdx.z;
  const int Kh = K >> 1;

  const ushort_t* ga = A  + (size_t)(bm + r0) * K + (size_t)z * Kh + koff;
  const ushort_t* gb = Bt + (size_t)(bn + r0) * K + (size_t)z * Kh + koff;
  ushort_t* Pz = P + (size_t)z * T_ * N;
  const int ldst = tid * 8;
  const int swz = l16 & 7;
  const int NT = Kh >> 6;

  floatx4 acc[4][4] = {};
  #pragma unroll
  for (int j = 0; j < 4; ++j) {
    __builtin_amdgcn_global_load_lds(GLB_AS(ga + (size_t)(j * 32) * K), LDS_AS(&Alds[0][ldst + j * 2048]), 16, 0, 0);
    __builtin_amdgcn_global_load_lds(GLB_AS(gb + (size_t)(j * 32) * K), LDS_AS(&Blds[0][ldst + j * 2048]), 16, 0, 0);
  }
  __syncthreads();

  int cur = 0;
  for (int t = 0; t < NT; ++t) {
    if (t + 1 < NT) {
      const int k0 = (t + 1) << 6;
      #pragma unroll
      for (int j = 0; j < 4; ++j) {
        __builtin_amdgcn_global_load_lds(GLB_AS(ga + k0 + (size_t)(j * 32) * K), LDS_AS(&Alds[cur ^ 1][ldst + j * 2048]), 16, 0, 0);
        __builtin_amdgcn_global_load_lds(GLB_AS(gb + k0 + (size_t)(j * 32) * K), LDS_AS(&Blds[cur ^ 1][ldst + j * 2048]), 16, 0, 0);
      }
    }
    #pragma unroll
    for (int kk = 0; kk < 2; ++kk) {
      short8 af[4], bf[4];
      #pragma unroll
      for (int fi = 0; fi < 4; ++fi) {
        const int row = m0 + fi * 16 + l16;
        af[fi] = *(const short8*)&Alds[cur][row * 64 + ((((kk << 2) + quad) ^ swz) * 8)];
      }
      #pragma unroll
      for (int fj = 0; fj < 4; ++fj) {
        const int row = n0 + fj * 16 + l16;
        bf[fj] = *(const short8*)&Blds[cur][row * 64 + ((((kk << 2) + quad) ^ swz) * 8)];
      }
      #pragma unroll
      for (int fi = 0; fi < 4; ++fi)
        #pragma unroll
        for (int fj = 0; fj < 4; ++fj)
          acc[fi][fj] = __builtin_amdgcn_mfma_f32_16x16x32_bf16(af[fi], bf[fj], acc[fi][fj], 0, 0, 0);
    }
    __syncthreads();
    cur ^= 1;
  }
  #pragma unroll
  for (int fi = 0; fi < 4; ++fi) {
    #pragma unroll
    for (int fj = 0; fj < 4; ++fj) {
      const int row = bm + m0 + fi * 16 + quad * 4;
      const int col = bn + n0 + fj * 16 + l16;
      const float bv = (z == 0) ? bias[col] : 0.0f;
      #pragma unroll
      for (int r = 0; r < 4; ++r) {
        float v = acc[fi][fj][r] + bv;
        Pz[(size_t)(row + r) * N + col] = f2b(v);
      }
    }
  }
}

// ---------------------------------------------------------------------------
// MFMA flash attention, FIXED-SHIFT softmax (shift-invariant; scores bounded
// for LN-scale data) + T14 stage-ahead K/V regs + T5 setprio + bit-packed
// mask + XCD-grouped 1D grid.
// ---------------------------------------------------------------------------
__global__ __launch_bounds__(256) void attn_mfma(const ushort_t* __restrict__ qkv,
                                                 const ushort_t* __restrict__ vT,
                                                 const unsigned long long* __restrict__ mbits,
                                                 ushort_t* __restrict__ o) {
  __shared__ ushort_t Qs[64][72];
  __shared__ ushort_t Ks[64][72];
  __shared__ ushort_t Vt[64][72];
  __shared__ ushort_t Ps[64][72];
  const int F = blockIdx.x;
  const int xcd = F & 7;
  const int sfl = F >> 3;
  const int qt = sfl & 7;
  const int gg = sfl >> 3;              // 0..23
  const int bh = gg * 8 + xcd;          // 0..191
  const int b = bh / 12, hh = bh - b * 12;
  const int tid = threadIdx.x;
  const int lane = tid & 63, w = tid >> 6;
  const int l16 = lane & 15, quad = lane >> 4;

  for (int c = tid; c < 1024; c += 256) {
    const int row = c >> 4, e0 = (c & 15) * 4;
    *(ushort4*)&Qs[row][e0] =
        *(const ushort4*)(qkv + ((size_t)(b * S_ + qt * 64 + row)) * QKVN + hh * 64 + e0);
  }

  floatx4 Oa[4] = {};
  float lrow[4] = {};
  const ushort_t* vbase = vT + ((size_t)(b * H_ + hh) * 64) * S_;

  // prologue: kt=0 K/V into registers
  ushort4 kreg[4], vreg[4];
  #pragma unroll
  for (int i = 0; i < 4; ++i) {
    const int c = tid + i * 256;
    const int row = c >> 4, e0 = (c & 15) * 4;
    kreg[i] = *(const ushort4*)(qkv + ((size_t)(b * S_ + row)) * QKVN + 768 + hh * 64 + e0);
    vreg[i] = *(const ushort4*)(vbase + (size_t)row * S_ + e0);
  }

  for (int kt = 0; kt < 8; ++kt) {
    __syncthreads();   // all waves done with previous tile's LDS
    #pragma unroll
    for (int i = 0; i < 4; ++i) {
      const int c = tid + i * 256;
      const int row = c >> 4, e0 = (c & 15) * 4;
      *(ushort4*)&Ks[row][e0] = kreg[i];
      *(ushort4*)&Vt[row][e0] = vreg[i];
    }
    if (kt < 7) {       // issue next tile's loads; latency hides under compute
      #pragma unroll
      for (int i = 0; i < 4; ++i) {
        const int c = tid + i * 256;
        const int row = c >> 4, e0 = (c & 15) * 4;
        kreg[i] = *(const ushort4*)(qkv + ((size_t)(b * S_ + (kt + 1) * 64 + row)) * QKVN + 768 + hh * 64 + e0);
        vreg[i] = *(const ushort4*)(vbase + (size_t)row * S_ + (kt + 1) * 64 + e0);
      }
    }
    __syncthreads();

    floatx4 sa[4] = {};
    __builtin_amdgcn_s_setprio(1);
    #pragma unroll
    for (int st = 0; st < 2; ++st) {
      short8 aq = *(const short8*)&Qs[w * 16 + l16][st * 32 + quad * 8];
      #pragma unroll
      for (int fj = 0; fj < 4; ++fj) {
        short8 bk = *(const short8*)&Ks[fj * 16 + l16][st * 32 + quad * 8];
        sa[fj] = __builtin_amdgcn_mfma_f32_16x16x32_bf16(aq, bk, sa[fj], 0, 0, 0);
      }
    }
    __builtin_amdgcn_s_setprio(0);

    #pragma unroll
    for (int r = 0; r < 4; ++r) {
      const int qrow = qt * 64 + w * 16 + quad * 4 + r;
      const unsigned long long m64 = mbits[((size_t)(b * S_ + qrow) << 3) + kt];
      // fixed shift: p = exp(s*0.125 + mask - 16); masked -> exp(-1e9) = 0
      float p0 = __expf(fmaf(sa[0][r], 0.125f, ((m64 >> l16) & 1ull)        ? -1e9f : -16.0f));
      float p1 = __expf(fmaf(sa[1][r], 0.125f, ((m64 >> (16 + l16)) & 1ull) ? -1e9f : -16.0f));
      float p2 = __expf(fmaf(sa[2][r], 0.125f, ((m64 >> (32 + l16)) & 1ull) ? -1e9f : -16.0f));
      float p3 = __expf(fmaf(sa[3][r], 0.125f, ((m64 >> (48 + l16)) & 1ull) ? -1e9f : -16.0f));
      const int prow = w * 16 + quad * 4 + r;
      Ps[prow][ 0 + l16] = f2b(p0);
      Ps[prow][16 + l16] = f2b(p1);
      Ps[prow][32 + l16] = f2b(p2);
      Ps[prow][48 + l16] = f2b(p3);
      lrow[r] += (p0 + p1) + (p2 + p3);   // per-lane partial; reduced once at end
    }

    __builtin_amdgcn_s_setprio(1);
    #pragma unroll
    for (int st = 0; st < 2; ++st) {
      short8 ap = *(const short8*)&Ps[w * 16 + l16][st * 32 + quad * 8];
      #pragma unroll
      for (int fe = 0; fe < 4; ++fe) {
        short8 bv = *(const short8*)&Vt[fe * 16 + l16][st * 32 + quad * 8];
        Oa[fe] = __builtin_amdgcn_mfma_f32_16x16x32_bf16(ap, bv, Oa[fe], 0, 0, 0);
      }
    }
    __builtin_amdgcn_s_setprio(0);
  }

  #pragma unroll
  for (int r = 0; r < 4; ++r) {
    float rs = lrow[r];
    rs += __shfl_xor(rs, 1); rs += __shfl_xor(rs, 2);
    rs += __shfl_xor(rs, 4); rs += __shfl_xor(rs, 8);
    const float inv = 1.0f / rs;
    const size_t tok = (size_t)(b * S_ + qt * 64 + w * 16 + quad * 4 + r);
    #pragma unroll
    for (int fe = 0; fe < 4; ++fe)
      o[tok * D_ + hh * 64 + fe * 16 + l16] = f2b(Oa[fe][r] * inv);
  }
}

// ---------------------------------------------------------------------------
// add_ln: h = LN(h + r0 + r1), r1 = r0 + T*D (two bf16 split-K partials).
// ---------------------------------------------------------------------------
__global__ __launch_bounds__(256) void add_ln(float* __restrict__ h,
                                              const ushort_t* __restrict__ r,
                                              const float* __restrict__ g,
                                              const float* __restrict__ be,
                                              ushort_t* __restrict__ h16) {
  const int t = blockIdx.x;
  const int tid = threadIdx.x;
  __shared__ float red[8];
  const size_t base = (size_t)t * D_;
  float x0 = h[base + tid]       + b2f(r[base + tid])       + b2f(r[TDC + base + tid]);
  float x1 = h[base + tid + 256] + b2f(r[base + tid + 256]) + b2f(r[TDC + base + tid + 256]);
  float x2 = h[base + tid + 512] + b2f(r[base + tid + 512]) + b2f(r[TDC + base + tid + 512]);
  float s = x0 + x1 + x2;
  #pragma unroll
  for (int off = 32; off > 0; off >>= 1) s += __shfl_down(s, off);
  if ((tid & 63) == 0) red[tid >> 6] = s;
  __syncthreads();
  if (tid == 0) red[4] = (red[0] + red[1] + red[2] + red[3]) * (1.0f / 768.0f);
  __syncthreads();
  const float m = red[4];
  float d0 = x0 - m, d1 = x1 - m, d2 = x2 - m;
  float s2 = d0 * d0 + d1 * d1 + d2 * d2;
  #pragma unroll
  for (int off = 32; off > 0; off >>= 1) s2 += __shfl_down(s2, off);
  if ((tid & 63) == 0) red[tid >> 6] = s2;
  __syncthreads();
  if (tid == 0) red[5] = (red[0] + red[1] + red[2] + red[3]) * (1.0f / 768.0f);
  __syncthreads();
  const float rs = rsqrtf(red[5] + 1e-5f);
  float y0 = d0 * rs * g[tid]       + be[tid];
  float y1 = d1 * rs * g[tid + 256] + be[tid + 256];
  float y2 = d2 * rs * g[tid + 512] + be[tid + 512];
  h[base + tid]       = y0; h16[base + tid]       = f2b(y0);
  h[base + tid + 256] = y1; h16[base + tid + 256] = f2b(y1);
  h[base + tid + 512] = y2; h16[base + tid + 512] = f2b(y2);
}

__global__ __launch_bounds__(256) void write_out(const float* __restrict__ h,
                                                 float* __restrict__ out, int n) {
  int i = blockIdx.x * 256 + threadIdx.x;
  if (i < n) out[i] = h[i];
}

// ---------------------------------------------------------------------------
extern "C" void kernel_launch(void* const* d_in, const int* in_sizes, int n_in,
                              void* d_out, int out_size, void* d_ws, size_t ws_size,
                              hipStream_t stream) {
  (void)in_sizes; (void)n_in; (void)out_size; (void)ws_size;
  const int* x    = (const int*)d_in[0];
  const int* mask = (const int*)d_in[1];
  const float* emb = (const float*)d_in[2];
  const float* Wq  = (const float*)d_in[3];
  const float* bq  = (const float*)d_in[4];
  const float* Wk  = (const float*)d_in[5];
  const float* bk  = (const float*)d_in[6];
  const float* Wv  = (const float*)d_in[7];
  const float* bv  = (const float*)d_in[8];
  const float* Wo  = (const float*)d_in[9];
  const float* bo  = (const float*)d_in[10];
  const float* W1  = (const float*)d_in[11];
  const float* b1  = (const float*)d_in[12];
  const float* W2  = (const float*)d_in[13];
  const float* b2  = (const float*)d_in[14];
  const float* g1  = (const float*)d_in[15];
  const float* be1 = (const float*)d_in[16];
  const float* g2  = (const float*)d_in[17];
  const float* be2 = (const float*)d_in[18];

  const size_t TD  = TDC;                        // 6,291,456
  const size_t DD  = (size_t)D_ * D_;            // 589,824
  const size_t WDD = (size_t)L_ * DD;
  const size_t WDF = (size_t)L_ * D_ * F_;

  float* h32 = (float*)d_ws;                     // 24 MB
  ushort_t* h16  = (ushort_t*)(h32 + TD);
  ushort_t* qkv16 = h16 + TD;                    // [T][2304] = 3*TD
  ushort_t* o1   = qkv16 + 3 * TD;
  ushort_t* o2   = o1 + TD;
  ushort_t* ff   = qkv16;                        // [T][3072] aliases qkv16|o1
  ushort_t* vT   = o2 + TD;                      // [B*H][64][512]  (= o2+TD)
  ushort_t* bias16 = vT + TD;                    // region reused for mask bits
  ushort_t* WqkvT = bias16 + (size_t)B_ * S_ * S_;  // [L][2304][768]
  ushort_t* WoT  = WqkvT + 3 * WDD;
  ushort_t* W1T  = WoT + WDD;
  ushort_t* W2T  = W1T + WDF;
  float* bqkv    = (float*)(W2T + WDF);          // [L][2304]
  int* xstride   = (int*)(bqkv + (size_t)L_ * QKVN);
  float* pe32    = (float*)o1;                   // [S][D] — o1 dead at setup
  unsigned long long* mbits = (unsigned long long*)bias16;  // [B*S][8], 512KB

  probe_x<<<dim3(1), 64, 0, stream>>>(x, xstride);
  pe_kernel<<<dim3(S_), 256, 0, stream>>>(pe32);
  transpose_cast<<<dim3(2, 24, 72), 256, 0, stream>>>(Wq, WqkvT,          768, 64, 12, 3 * DD, (size_t)64 * 768);
  transpose_cast<<<dim3(2, 24, 72), 256, 0, stream>>>(Wk, WqkvT + DD,     768, 64, 12, 3 * DD, (size_t)64 * 768);
  transpose_cast<<<dim3(2, 24, 72), 256, 0, stream>>>(Wv, WqkvT + 2 * DD, 768, 64, 12, 3 * DD, (size_t)64 * 768);
  transpose_cast<<<dim3(24, 24, 6), 256, 0, stream>>>(Wo, WoT, 768, 768, 1, DD, 0);
  transpose_cast<<<dim3(96, 24, 6), 256, 0, stream>>>(W1, W1T, 768, 3072, 1, (size_t)D_ * F_, 0);
  transpose_cast<<<dim3(24, 96, 6), 256, 0, stream>>>(W2, W2T, 3072, 768, 1, (size_t)D_ * F_, 0);
  pack_bias<<<dim3((L_ * D_ + 255) / 256), 256, 0, stream>>>(bq, bk, bv, bqkv);
  mask_bits<<<dim3((B_ * S_ * S_) / 256), 256, 0, stream>>>(mask, mbits);
  embed_pe<<<dim3(T_), 256, 0, stream>>>(x, xstride, emb, pe32, h32, h16);

  const dim3 gQKV(QKVN / 128, T_ / 128);     // 18 x 64
  const dim3 gDsk(D_ / 128, T_ / 128, 2);    // 6 x 64 x 2 (split-K)
  const dim3 gF(F_ / 128, T_ / 128);         // 24 x 64
  for (int l = 0; l < L_; ++l) {
    const size_t oDD = (size_t)l * DD;
    const size_t oDF = (size_t)l * D_ * F_;
    gemm_mfma<0><<<gQKV, 256, 0, stream>>>(h16, WqkvT + (size_t)l * 3 * DD, bqkv + (size_t)l * QKVN, qkv16, QKVN, D_);
    transpose_v<<<dim3(16, 2, B_ * H_), 256, 0, stream>>>(qkv16, vT);
    attn_mfma<<<dim3(8 * H_ * B_), 256, 0, stream>>>(qkv16, vT, mbits, o1);
    // Wo split-K: partials -> o2 (z=0) and vT (z=1, = o2+TD); vT dead after attn.
    gemm_mfma_sk<<<gDsk, 256, 0, stream>>>(o1, WoT + oDD, bo + l * D_, o2, D_, D_);
    add_ln<<<dim3(T_), 256, 0, stream>>>(h32, o2, g1 + l * D_, be1 + l * D_, h16);
    gemm_mfma<1><<<gF, 256, 0, stream>>>(h16, W1T + oDF, b1 + l * F_, ff, F_, D_);
    // FF2 split-K: partials -> o2 (z=0) and vT (z=1) — same safe pair.
    gemm_mfma_sk<<<gDsk, 256, 0, stream>>>(ff, W2T + oDF, b2 + l * D_, o2, D_, F_);
    add_ln<<<dim3(T_), 256, 0, stream>>>(h32, o2, g2 + l * D_, be2 + l * D_, h16);
  }
  write_out<<<dim3((unsigned)(TD / 256)), 256, 0, stream>>>(h32, (float*)d_out, (int)TD);
}

// Round 9
// 1771.354 us; speedup vs baseline: 1.0913x; 1.0913x over previous
//
#include <hip/hip_runtime.h>
#include <hip/hip_bf16.h>
#include <math.h>

#define B_  16
#define S_  512
#define D_  768
#define H_  12
#define DN_ 64
#define F_  3072
#define L_  6
#define T_  (B_*S_)          // 8192 tokens
#define QKVN 2304            // 3*D
#define TDC ((size_t)T_*D_)  // 6,291,456

typedef unsigned short ushort_t;
typedef short short8 __attribute__((ext_vector_type(8)));
typedef float floatx4 __attribute__((ext_vector_type(4)));

#define LDS_AS(p) ((__attribute__((address_space(3))) void*)(p))
#define GLB_AS(p) ((const __attribute__((address_space(1))) void*)(p))

static __device__ __forceinline__ float b2f(ushort_t u) {
  union { unsigned int i; float f; } x; x.i = ((unsigned int)u) << 16; return x.f;
}
static __device__ __forceinline__ ushort_t f2b(float f) {
  union { float f; unsigned int i; } x; x.f = f;
  unsigned int r = x.i + 0x7fffu + ((x.i >> 16) & 1u);   // RNE
  return (ushort_t)(r >> 16);
}

// ---------------------------------------------------------------------------
__global__ __launch_bounds__(64) void probe_x(const int* __restrict__ x,
                                              int* __restrict__ xstride) {
  if (threadIdx.x == 0) {
    int allzero = 1;
    for (int i = 0; i < 64; ++i) allzero &= (x[2 * i + 1] == 0) ? 1 : 0;
    *xstride = allzero ? 2 : 1;
  }
}

// ---------------------------------------------------------------------------
// One-time positional-encoding table pe[S][D] (f32).
// ---------------------------------------------------------------------------
__global__ __launch_bounds__(256) void pe_kernel(float* __restrict__ pe) {
  const int s = blockIdx.x;
  const float pos = (float)s;
  for (int d = threadIdx.x; d < D_; d += 256) {
    float v;
    if ((d & 1) == 0) {
      float freq = powf(10000.0f, -(float)d * (1.0f / 768.0f));
      v = sinf(pos * freq);
    } else {
      float freq = powf(10000.0f, -(float)(d + 1) * (1.0f / 768.0f));
      v = cosf(pos * freq);
    }
    pe[(size_t)s * D_ + d] = v;
  }
}

// ---------------------------------------------------------------------------
__global__ __launch_bounds__(256) void embed_pe(const int* __restrict__ x,
                                                const int* __restrict__ xstride,
                                                const float* __restrict__ emb,
                                                const float* __restrict__ pe,
                                                float* __restrict__ h32,
                                                ushort_t* __restrict__ h16) {
  const int t = blockIdx.x;
  const int s = t & (S_ - 1);
  const int tok = x[t * (*xstride)];
  const float* ep = emb + (size_t)tok * D_;
  const float* pp = pe + (size_t)s * D_;
  for (int d = threadIdx.x; d < D_; d += 256) {
    float v = ep[d] + pp[d];
    h32[(size_t)t * D_ + d] = v;
    h16[(size_t)t * D_ + d] = f2b(v);
  }
}

// ---------------------------------------------------------------------------
// Bit-pack padding mask: mask[B][S][S] (int 0/1) -> bits[B*S][8] uint64.
// ---------------------------------------------------------------------------
__global__ __launch_bounds__(256) void mask_bits(const int* __restrict__ mask,
                                                 unsigned long long* __restrict__ bits) {
  const int gw = (blockIdx.x * 256 + threadIdx.x) >> 6;   // global wave id
  const int lane = threadIdx.x & 63;
  const int m = mask[(size_t)gw * 64 + lane];
  unsigned long long bal = __ballot(m != 0);
  if (lane == 0) bits[gw] = bal;
}

// ---------------------------------------------------------------------------
// pack bq/bk/bv [L][768] each -> bqkv [L][2304]
// ---------------------------------------------------------------------------
__global__ __launch_bounds__(256) void pack_bias(const float* __restrict__ bq,
                                                 const float* __restrict__ bk,
                                                 const float* __restrict__ bv,
                                                 float* __restrict__ bqkv) {
  const int i = blockIdx.x * 256 + threadIdx.x;   // l*768+c, i < 4608
  if (i < L_ * D_) {
    const int l = i / D_, c = i - l * D_;
    bqkv[(size_t)l * QKVN + c]          = bq[i];
    bqkv[(size_t)l * QKVN + 768 + c]    = bk[i];
    bqkv[(size_t)l * QKVN + 1536 + c]   = bv[i];
  }
}

// ---------------------------------------------------------------------------
// Batched transpose-cast fp32 [z][R][C] -> bf16 out rows.
// ---------------------------------------------------------------------------
__global__ __launch_bounds__(256) void transpose_cast(const float* __restrict__ in,
                                                      ushort_t* __restrict__ out,
                                                      int R, int C, int ZH,
                                                      size_t strideL, size_t strideH) {
  __shared__ float tb[32][33];
  const int c0 = blockIdx.x * 32, r0 = blockIdx.y * 32;
  const int z = blockIdx.z;
  const float* ib = in + (size_t)z * R * C;
  ushort_t* ob = out + (size_t)(z / ZH) * strideL + (size_t)(z % ZH) * strideH;
  const int i = threadIdx.x >> 5;
  const int j = threadIdx.x & 31;
  #pragma unroll
  for (int t = 0; t < 4; ++t)
    tb[i + 8 * t][j] = ib[(size_t)(r0 + i + 8 * t) * C + c0 + j];
  __syncthreads();
  #pragma unroll
  for (int t = 0; t < 4; ++t)
    ob[(size_t)(c0 + i + 8 * t) * R + r0 + j] = f2b(tb[j][i + 8 * t]);
}

// ---------------------------------------------------------------------------
// qkv [B*S][2304] (v at +1536) -> vT [B*H][64 e][512 s]
// ---------------------------------------------------------------------------
__global__ __launch_bounds__(256) void transpose_v(const ushort_t* __restrict__ qkv,
                                                   ushort_t* __restrict__ vT) {
  __shared__ ushort_t tb[32][33];
  const int s0 = blockIdx.x * 32, e0 = blockIdx.y * 32;
  const int bh = blockIdx.z;
  const int b = bh / 12, hh = bh - b * 12;
  const int i = threadIdx.x >> 5, j = threadIdx.x & 31;
  #pragma unroll
  for (int t = 0; t < 4; ++t)
    tb[i + 8 * t][j] = qkv[((size_t)(b * S_ + s0 + i + 8 * t)) * QKVN + 1536 + hh * 64 + e0 + j];
  __syncthreads();
  #pragma unroll
  for (int t = 0; t < 4; ++t)
    vT[((size_t)(bh * 64 + e0 + i + 8 * t)) * S_ + s0 + j] = tb[j][i + 8 * t];
}

// ---------------------------------------------------------------------------
// MFMA GEMM (QKV/FF1 — long grids, occupancy-insensitive): 128x128, BK=64,
// both-sides XOR swizzle, T3-minimum double-buffered schedule (prefetch next
// tile before compute, one barrier per K-step). 64KB LDS -> 2 blocks/CU is
// fine here (grid >= 1152 blocks stays balanced).
// ---------------------------------------------------------------------------
template<int RELU>
__global__ __launch_bounds__(256) void gemm_mfma(const ushort_t* __restrict__ A,
                                                 const ushort_t* __restrict__ Bt,
                                                 const float* __restrict__ bias,
                                                 ushort_t* __restrict__ C,
                                                 int N, int K) {
  __shared__ ushort_t Alds[2][128 * 64];
  __shared__ ushort_t Blds[2][128 * 64];
  const int tid = threadIdx.x;
  const int lane = tid & 63, wave = tid >> 6;
  const int l16 = lane & 15, quad = lane >> 4;
  const int m0 = (wave >> 1) * 64, n0 = (wave & 1) * 64;
  const int nb = gridDim.x;
  const int flat = blockIdx.y * nb + blockIdx.x;
  const int grp = flat / (8 * nb);
  const int rem = flat - grp * 8 * nb;
  const int bm = (grp * 8 + (rem & 7)) * 128;
  const int bn = (rem >> 3) * 128;
  const int r0 = tid >> 3;
  const int ch = tid & 7;
  const int koff = (ch ^ (r0 & 7)) * 8;      // pre-swizzled source column

  const ushort_t* ga = A  + (size_t)(bm + r0) * K + koff;
  const ushort_t* gb = Bt + (size_t)(bn + r0) * K + koff;
  const int ldst = tid * 8;                  // per-thread LDS slot (16B)
  const int swz = l16 & 7;
  const int NT = K >> 6;

  floatx4 acc[4][4] = {};
  // prologue: stage tile 0 into buffer 0, drain
  #pragma unroll
  for (int j = 0; j < 4; ++j) {
    __builtin_amdgcn_global_load_lds(GLB_AS(ga + (size_t)(j * 32) * K), LDS_AS(&Alds[0][ldst + j * 2048]), 16, 0, 0);
    __builtin_amdgcn_global_load_lds(GLB_AS(gb + (size_t)(j * 32) * K), LDS_AS(&Blds[0][ldst + j * 2048]), 16, 0, 0);
  }
  __syncthreads();

  int cur = 0;
  for (int t = 0; t < NT; ++t) {
    if (t + 1 < NT) {   // issue next tile's loads; latency hides under MFMA
      const int k0 = (t + 1) << 6;
      #pragma unroll
      for (int j = 0; j < 4; ++j) {
        __builtin_amdgcn_global_load_lds(GLB_AS(ga + k0 + (size_t)(j * 32) * K), LDS_AS(&Alds[cur ^ 1][ldst + j * 2048]), 16, 0, 0);
        __builtin_amdgcn_global_load_lds(GLB_AS(gb + k0 + (size_t)(j * 32) * K), LDS_AS(&Blds[cur ^ 1][ldst + j * 2048]), 16, 0, 0);
      }
    }
    #pragma unroll
    for (int kk = 0; kk < 2; ++kk) {
      short8 af[4], bf[4];
      #pragma unroll
      for (int fi = 0; fi < 4; ++fi) {
        const int row = m0 + fi * 16 + l16;
        af[fi] = *(const short8*)&Alds[cur][row * 64 + ((((kk << 2) + quad) ^ swz) * 8)];
      }
      #pragma unroll
      for (int fj = 0; fj < 4; ++fj) {
        const int row = n0 + fj * 16 + l16;
        bf[fj] = *(const short8*)&Blds[cur][row * 64 + ((((kk << 2) + quad) ^ swz) * 8)];
      }
      #pragma unroll
      for (int fi = 0; fi < 4; ++fi)
        #pragma unroll
        for (int fj = 0; fj < 4; ++fj)
          acc[fi][fj] = __builtin_amdgcn_mfma_f32_16x16x32_bf16(af[fi], bf[fj], acc[fi][fj], 0, 0, 0);
    }
    __syncthreads();    // vmcnt(0): next tile landed; all waves done with cur
    cur ^= 1;
  }
  #pragma unroll
  for (int fi = 0; fi < 4; ++fi) {
    #pragma unroll
    for (int fj = 0; fj < 4; ++fj) {
      const int row = bm + m0 + fi * 16 + quad * 4;
      const int col = bn + n0 + fj * 16 + l16;
      const float bv = bias[col];
      #pragma unroll
      for (int r = 0; r < 4; ++r) {
        float v = acc[fi][fj][r] + bv;
        if (RELU) v = fmaxf(v, 0.0f);
        C[(size_t)(row + r) * N + col] = f2b(v);
      }
    }
  }
}

// ---------------------------------------------------------------------------
// Split-K (x2) GEMM (Wo, FF2): SINGLE-buffer BK=64+swizzle (32KB LDS).
// Occupancy-critical: grid 768 blocks needs exactly 3 blocks/CU residency;
// 64KB dbuf capped it at 2 -> 2:1 imbalance (R8 regression). Keep 32KB.
// ---------------------------------------------------------------------------
__global__ __launch_bounds__(256) void gemm_mfma_sk(const ushort_t* __restrict__ A,
                                                    const ushort_t* __restrict__ Bt,
                                                    const float* __restrict__ bias,
                                                    ushort_t* __restrict__ P,
                                                    int N, int K) {
  __shared__ ushort_t Alds[128 * 64];
  __shared__ ushort_t Blds[128 * 64];
  const int tid = threadIdx.x;
  const int lane = tid & 63, wave = tid >> 6;
  const int l16 = lane & 15, quad = lane >> 4;
  const int m0 = (wave >> 1) * 64, n0 = (wave & 1) * 64;
  const int nb = gridDim.x;
  const int flat = blockIdx.y * nb + blockIdx.x;
  const int grp = flat / (8 * nb);
  const int rem = flat - grp * 8 * nb;
  const int bm = (grp * 8 + (rem & 7)) * 128;
  const int bn = (rem >> 3) * 128;
  const int r0 = tid >> 3;
  const int ch = tid & 7;
  const int koff = (ch ^ (r0 & 7)) * 8;
  const int z = blockIdx.z;
  const int Kh = K >> 1;

  const ushort_t* ga = A  + (size_t)(bm + r0) * K + (size_t)z * Kh + koff;
  const ushort_t* gb = Bt + (size_t)(bn + r0) * K + (size_t)z * Kh + koff;
  ushort_t* la = &Alds[tid * 8];
  ushort_t* lb = &Blds[tid * 8];
  ushort_t* Pz = P + (size_t)z * T_ * N;
  const int swz = l16 & 7;

  floatx4 acc[4][4] = {};
  for (int k0 = 0; k0 < Kh; k0 += 64) {
    __syncthreads();
    #pragma unroll
    for (int j = 0; j < 4; ++j) {
      __builtin_amdgcn_global_load_lds(GLB_AS(ga + k0 + (size_t)(j * 32) * K), LDS_AS(la + j * 2048), 16, 0, 0);
      __builtin_amdgcn_global_load_lds(GLB_AS(gb + k0 + (size_t)(j * 32) * K), LDS_AS(lb + j * 2048), 16, 0, 0);
    }
    __syncthreads();
    #pragma unroll
    for (int kk = 0; kk < 2; ++kk) {
      short8 af[4], bf[4];
      #pragma unroll
      for (int fi = 0; fi < 4; ++fi) {
        const int row = m0 + fi * 16 + l16;
        af[fi] = *(const short8*)&Alds[row * 64 + ((((kk << 2) + quad) ^ swz) * 8)];
      }
      #pragma unroll
      for (int fj = 0; fj < 4; ++fj) {
        const int row = n0 + fj * 16 + l16;
        bf[fj] = *(const short8*)&Blds[row * 64 + ((((kk << 2) + quad) ^ swz) * 8)];
      }
      #pragma unroll
      for (int fi = 0; fi < 4; ++fi)
        #pragma unroll
        for (int fj = 0; fj < 4; ++fj)
          acc[fi][fj] = __builtin_amdgcn_mfma_f32_16x16x32_bf16(af[fi], bf[fj], acc[fi][fj], 0, 0, 0);
    }
  }
  #pragma unroll
  for (int fi = 0; fi < 4; ++fi) {
    #pragma unroll
    for (int fj = 0; fj < 4; ++fj) {
      const int row = bm + m0 + fi * 16 + quad * 4;
      const int col = bn + n0 + fj * 16 + l16;
      const float bv = (z == 0) ? bias[col] : 0.0f;
      #pragma unroll
      for (int r = 0; r < 4; ++r) {
        float v = acc[fi][fj][r] + bv;
        Pz[(size_t)(row + r) * N + col] = f2b(v);
      }
    }
  }
}

// ---------------------------------------------------------------------------
// MFMA flash attention, FIXED-SHIFT softmax (shift-invariant; scores bounded
// for LN-scale data) + T14 stage-ahead K/V regs + T5 setprio + bit-packed
// mask + XCD-grouped 1D grid.
// ---------------------------------------------------------------------------
__global__ __launch_bounds__(256) void attn_mfma(const ushort_t* __restrict__ qkv,
                                                 const ushort_t* __restrict__ vT,
                                                 const unsigned long long* __restrict__ mbits,
                                                 ushort_t* __restrict__ o) {
  __shared__ ushort_t Qs[64][72];
  __shared__ ushort_t Ks[64][72];
  __shared__ ushort_t Vt[64][72];
  __shared__ ushort_t Ps[64][72];
  const int F = blockIdx.x;
  const int xcd = F & 7;
  const int sfl = F >> 3;
  const int qt = sfl & 7;
  const int gg = sfl >> 3;              // 0..23
  const int bh = gg * 8 + xcd;          // 0..191
  const int b = bh / 12, hh = bh - b * 12;
  const int tid = threadIdx.x;
  const int lane = tid & 63, w = tid >> 6;
  const int l16 = lane & 15, quad = lane >> 4;

  for (int c = tid; c < 1024; c += 256) {
    const int row = c >> 4, e0 = (c & 15) * 4;
    *(ushort4*)&Qs[row][e0] =
        *(const ushort4*)(qkv + ((size_t)(b * S_ + qt * 64 + row)) * QKVN + hh * 64 + e0);
  }

  floatx4 Oa[4] = {};
  float lrow[4] = {};
  const ushort_t* vbase = vT + ((size_t)(b * H_ + hh) * 64) * S_;

  // prologue: kt=0 K/V into registers
  ushort4 kreg[4], vreg[4];
  #pragma unroll
  for (int i = 0; i < 4; ++i) {
    const int c = tid + i * 256;
    const int row = c >> 4, e0 = (c & 15) * 4;
    kreg[i] = *(const ushort4*)(qkv + ((size_t)(b * S_ + row)) * QKVN + 768 + hh * 64 + e0);
    vreg[i] = *(const ushort4*)(vbase + (size_t)row * S_ + e0);
  }

  for (int kt = 0; kt < 8; ++kt) {
    __syncthreads();   // all waves done with previous tile's LDS
    #pragma unroll
    for (int i = 0; i < 4; ++i) {
      const int c = tid + i * 256;
      const int row = c >> 4, e0 = (c & 15) * 4;
      *(ushort4*)&Ks[row][e0] = kreg[i];
      *(ushort4*)&Vt[row][e0] = vreg[i];
    }
    if (kt < 7) {       // issue next tile's loads; latency hides under compute
      #pragma unroll
      for (int i = 0; i < 4; ++i) {
        const int c = tid + i * 256;
        const int row = c >> 4, e0 = (c & 15) * 4;
        kreg[i] = *(const ushort4*)(qkv + ((size_t)(b * S_ + (kt + 1) * 64 + row)) * QKVN + 768 + hh * 64 + e0);
        vreg[i] = *(const ushort4*)(vbase + (size_t)row * S_ + (kt + 1) * 64 + e0);
      }
    }
    __syncthreads();

    floatx4 sa[4] = {};
    __builtin_amdgcn_s_setprio(1);
    #pragma unroll
    for (int st = 0; st < 2; ++st) {
      short8 aq = *(const short8*)&Qs[w * 16 + l16][st * 32 + quad * 8];
      #pragma unroll
      for (int fj = 0; fj < 4; ++fj) {
        short8 bk = *(const short8*)&Ks[fj * 16 + l16][st * 32 + quad * 8];
        sa[fj] = __builtin_amdgcn_mfma_f32_16x16x32_bf16(aq, bk, sa[fj], 0, 0, 0);
      }
    }
    __builtin_amdgcn_s_setprio(0);

    #pragma unroll
    for (int r = 0; r < 4; ++r) {
      const int qrow = qt * 64 + w * 16 + quad * 4 + r;
      const unsigned long long m64 = mbits[((size_t)(b * S_ + qrow) << 3) + kt];
      // fixed shift: p = exp(s*0.125 + mask - 16); masked -> exp(-1e9) = 0
      float p0 = __expf(fmaf(sa[0][r], 0.125f, ((m64 >> l16) & 1ull)        ? -1e9f : -16.0f));
      float p1 = __expf(fmaf(sa[1][r], 0.125f, ((m64 >> (16 + l16)) & 1ull) ? -1e9f : -16.0f));
      float p2 = __expf(fmaf(sa[2][r], 0.125f, ((m64 >> (32 + l16)) & 1ull) ? -1e9f : -16.0f));
      float p3 = __expf(fmaf(sa[3][r], 0.125f, ((m64 >> (48 + l16)) & 1ull) ? -1e9f : -16.0f));
      const int prow = w * 16 + quad * 4 + r;
      Ps[prow][ 0 + l16] = f2b(p0);
      Ps[prow][16 + l16] = f2b(p1);
      Ps[prow][32 + l16] = f2b(p2);
      Ps[prow][48 + l16] = f2b(p3);
      lrow[r] += (p0 + p1) + (p2 + p3);   // per-lane partial; reduced once at end
    }

    __builtin_amdgcn_s_setprio(1);
    #pragma unroll
    for (int st = 0; st < 2; ++st) {
      short8 ap = *(const short8*)&Ps[w * 16 + l16][st * 32 + quad * 8];
      #pragma unroll
      for (int fe = 0; fe < 4; ++fe) {
        short8 bv = *(const short8*)&Vt[fe * 16 + l16][st * 32 + quad * 8];
        Oa[fe] = __builtin_amdgcn_mfma_f32_16x16x32_bf16(ap, bv, Oa[fe], 0, 0, 0);
      }
    }
    __builtin_amdgcn_s_setprio(0);
  }

  #pragma unroll
  for (int r = 0; r < 4; ++r) {
    float rs = lrow[r];
    rs += __shfl_xor(rs, 1); rs += __shfl_xor(rs, 2);
    rs += __shfl_xor(rs, 4); rs += __shfl_xor(rs, 8);
    const float inv = 1.0f / rs;
    const size_t tok = (size_t)(b * S_ + qt * 64 + w * 16 + quad * 4 + r);
    #pragma unroll
    for (int fe = 0; fe < 4; ++fe)
      o[tok * D_ + hh * 64 + fe * 16 + l16] = f2b(Oa[fe][r] * inv);
  }
}

// ---------------------------------------------------------------------------
// add_ln: h = LN(h + r0 + r1), r1 = r0 + T*D (two bf16 split-K partials).
// ---------------------------------------------------------------------------
__global__ __launch_bounds__(256) void add_ln(float* __restrict__ h,
                                              const ushort_t* __restrict__ r,
                                              const float* __restrict__ g,
                                              const float* __restrict__ be,
                                              ushort_t* __restrict__ h16) {
  const int t = blockIdx.x;
  const int tid = threadIdx.x;
  __shared__ float red[8];
  const size_t base = (size_t)t * D_;
  float x0 = h[base + tid]       + b2f(r[base + tid])       + b2f(r[TDC + base + tid]);
  float x1 = h[base + tid + 256] + b2f(r[base + tid + 256]) + b2f(r[TDC + base + tid + 256]);
  float x2 = h[base + tid + 512] + b2f(r[base + tid + 512]) + b2f(r[TDC + base + tid + 512]);
  float s = x0 + x1 + x2;
  #pragma unroll
  for (int off = 32; off > 0; off >>= 1) s += __shfl_down(s, off);
  if ((tid & 63) == 0) red[tid >> 6] = s;
  __syncthreads();
  if (tid == 0) red[4] = (red[0] + red[1] + red[2] + red[3]) * (1.0f / 768.0f);
  __syncthreads();
  const float m = red[4];
  float d0 = x0 - m, d1 = x1 - m, d2 = x2 - m;
  float s2 = d0 * d0 + d1 * d1 + d2 * d2;
  #pragma unroll
  for (int off = 32; off > 0; off >>= 1) s2 += __shfl_down(s2, off);
  if ((tid & 63) == 0) red[tid >> 6] = s2;
  __syncthreads();
  if (tid == 0) red[5] = (red[0] + red[1] + red[2] + red[3]) * (1.0f / 768.0f);
  __syncthreads();
  const float rs = rsqrtf(red[5] + 1e-5f);
  float y0 = d0 * rs * g[tid]       + be[tid];
  float y1 = d1 * rs * g[tid + 256] + be[tid + 256];
  float y2 = d2 * rs * g[tid + 512] + be[tid + 512];
  h[base + tid]       = y0; h16[base + tid]       = f2b(y0);
  h[base + tid + 256] = y1; h16[base + tid + 256] = f2b(y1);
  h[base + tid + 512] = y2; h16[base + tid + 512] = f2b(y2);
}

__global__ __launch_bounds__(256) void write_out(const float* __restrict__ h,
                                                 float* __restrict__ out, int n) {
  int i = blockIdx.x * 256 + threadIdx.x;
  if (i < n) out[i] = h[i];
}

// ---------------------------------------------------------------------------
extern "C" void kernel_launch(void* const* d_in, const int* in_sizes, int n_in,
                              void* d_out, int out_size, void* d_ws, size_t ws_size,
                              hipStream_t stream) {
  (void)in_sizes; (void)n_in; (void)out_size; (void)ws_size;
  const int* x    = (const int*)d_in[0];
  const int* mask = (const int*)d_in[1];
  const float* emb = (const float*)d_in[2];
  const float* Wq  = (const float*)d_in[3];
  const float* bq  = (const float*)d_in[4];
  const float* Wk  = (const float*)d_in[5];
  const float* bk  = (const float*)d_in[6];
  const float* Wv  = (const float*)d_in[7];
  const float* bv  = (const float*)d_in[8];
  const float* Wo  = (const float*)d_in[9];
  const float* bo  = (const float*)d_in[10];
  const float* W1  = (const float*)d_in[11];
  const float* b1  = (const float*)d_in[12];
  const float* W2  = (const float*)d_in[13];
  const float* b2  = (const float*)d_in[14];
  const float* g1  = (const float*)d_in[15];
  const float* be1 = (const float*)d_in[16];
  const float* g2  = (const float*)d_in[17];
  const float* be2 = (const float*)d_in[18];

  const size_t TD  = TDC;                        // 6,291,456
  const size_t DD  = (size_t)D_ * D_;            // 589,824
  const size_t WDD = (size_t)L_ * DD;
  const size_t WDF = (size_t)L_ * D_ * F_;

  float* h32 = (float*)d_ws;                     // 24 MB
  ushort_t* h16  = (ushort_t*)(h32 + TD);
  ushort_t* qkv16 = h16 + TD;                    // [T][2304] = 3*TD
  ushort_t* o1   = qkv16 + 3 * TD;
  ushort_t* o2   = o1 + TD;
  ushort_t* ff   = qkv16;                        // [T][3072] aliases qkv16|o1
  ushort_t* vT   = o2 + TD;                      // [B*H][64][512]  (= o2+TD)
  ushort_t* bias16 = vT + TD;                    // region reused for mask bits
  ushort_t* WqkvT = bias16 + (size_t)B_ * S_ * S_;  // [L][2304][768]
  ushort_t* WoT  = WqkvT + 3 * WDD;
  ushort_t* W1T  = WoT + WDD;
  ushort_t* W2T  = W1T + WDF;
  float* bqkv    = (float*)(W2T + WDF);          // [L][2304]
  int* xstride   = (int*)(bqkv + (size_t)L_ * QKVN);
  float* pe32    = (float*)o1;                   // [S][D] — o1 dead at setup
  unsigned long long* mbits = (unsigned long long*)bias16;  // [B*S][8], 512KB

  probe_x<<<dim3(1), 64, 0, stream>>>(x, xstride);
  pe_kernel<<<dim3(S_), 256, 0, stream>>>(pe32);
  transpose_cast<<<dim3(2, 24, 72), 256, 0, stream>>>(Wq, WqkvT,          768, 64, 12, 3 * DD, (size_t)64 * 768);
  transpose_cast<<<dim3(2, 24, 72), 256, 0, stream>>>(Wk, WqkvT + DD,     768, 64, 12, 3 * DD, (size_t)64 * 768);
  transpose_cast<<<dim3(2, 24, 72), 256, 0, stream>>>(Wv, WqkvT + 2 * DD, 768, 64, 12, 3 * DD, (size_t)64 * 768);
  transpose_cast<<<dim3(24, 24, 6), 256, 0, stream>>>(Wo, WoT, 768, 768, 1, DD, 0);
  transpose_cast<<<dim3(96, 24, 6), 256, 0, stream>>>(W1, W1T, 768, 3072, 1, (size_t)D_ * F_, 0);
  transpose_cast<<<dim3(24, 96, 6), 256, 0, stream>>>(W2, W2T, 3072, 768, 1, (size_t)D_ * F_, 0);
  pack_bias<<<dim3((L_ * D_ + 255) / 256), 256, 0, stream>>>(bq, bk, bv, bqkv);
  mask_bits<<<dim3((B_ * S_ * S_) / 256), 256, 0, stream>>>(mask, mbits);
  embed_pe<<<dim3(T_), 256, 0, stream>>>(x, xstride, emb, pe32, h32, h16);

  const dim3 gQKV(QKVN / 128, T_ / 128);     // 18 x 64
  const dim3 gDsk(D_ / 128, T_ / 128, 2);    // 6 x 64 x 2 (split-K)
  const dim3 gF(F_ / 128, T_ / 128);         // 24 x 64
  for (int l = 0; l < L_; ++l) {
    const size_t oDD = (size_t)l * DD;
    const size_t oDF = (size_t)l * D_ * F_;
    gemm_mfma<0><<<gQKV, 256, 0, stream>>>(h16, WqkvT + (size_t)l * 3 * DD, bqkv + (size_t)l * QKVN, qkv16, QKVN, D_);
    transpose_v<<<dim3(16, 2, B_ * H_), 256, 0, stream>>>(qkv16, vT);
    attn_mfma<<<dim3(8 * H_ * B_), 256, 0, stream>>>(qkv16, vT, mbits, o1);
    // Wo split-K: partials -> o2 (z=0) and vT (z=1, = o2+TD); vT dead after attn.
    gemm_mfma_sk<<<gDsk, 256, 0, stream>>>(o1, WoT + oDD, bo + l * D_, o2, D_, D_);
    add_ln<<<dim3(T_), 256, 0, stream>>>(h32, o2, g1 + l * D_, be1 + l * D_, h16);
    gemm_mfma<1><<<gF, 256, 0, stream>>>(h16, W1T + oDF, b1 + l * F_, ff, F_, D_);
    // FF2 split-K: partials -> o2 (z=0) and vT (z=1) — same safe pair.
    gemm_mfma_sk<<<gDsk, 256, 0, stream>>>(ff, W2T + oDF, b2 + l * D_, o2, D_, F_);
    add_ln<<<dim3(T_), 256, 0, stream>>>(h32, o2, g2 + l * D_, be2 + l * D_, h16);
  }
  write_out<<<dim3((unsigned)(TD / 256)), 256, 0, stream>>>(h32, (float*)d_out, (int)TD);
}